// Round 1
// baseline (713.547 us; speedup 1.0000x reference)
//
#include <hip/hip_runtime.h>
#include <math.h>

#define BB 32
#define HH 512
#define WW 512
#define NB 4096                      // 64*64 blocks per image
#define NTILES (BB * NB)             // 131072 tiles
#define QD 25165824                  // 32*3*4096*64  (qdct elements)
#define PP 16777216                  // 32*512*512*2  (enc_qf elements)
#define TAILOFF (2 * (size_t)QD + 2 * (size_t)PP)  // 83886080

__constant__ int c_zz[64] = {
    0,1,8,16,9,2,3,10,17,24,32,25,18,11,4,5,12,19,26,33,40,48,41,34,27,20,13,6,
    7,14,21,28,35,42,49,56,57,50,43,36,29,22,15,23,30,37,44,51,58,59,52,45,38,31,
    39,46,53,60,61,54,47,55,62,63};

__constant__ float c_yq[64] = {
    16,11,10,16,24,40,51,61, 12,12,14,19,26,58,60,55, 14,13,16,24,40,57,69,56,
    14,17,22,29,51,87,80,62, 18,22,37,56,68,109,103,77, 24,36,55,64,81,104,113,92,
    49,64,78,87,103,121,120,101, 72,92,95,98,112,100,103,99};

__constant__ float c_cq[64] = {
    17,18,24,47,99,99,99,99, 18,21,26,66,99,99,99,99, 24,26,56,99,99,99,99,99,
    47,66,99,99,99,99,99,99, 99,99,99,99,99,99,99,99, 99,99,99,99,99,99,99,99,
    99,99,99,99,99,99,99,99, 99,99,99,99,99,99,99,99};

__device__ __forceinline__ double qf_from_rank(double r) {
    double q = rint(2.0 + r * 48.0 + 0.0);     // QF_MIN + r*(QF_MAX-QF_MIN) + QF_BIAS
    return fmin(fmax(q, 2.0), 50.0);
}
__device__ __forceinline__ double scale_from_qf(double qf) {
    double s = (qf < 50.0) ? (5000.0 / qf) : (200.0 - 2.0 * qf);
    return rint(s) / 100.0;
}

struct TileSmem {
    double X[4][3][64];   // rounded ycbcr - 128, per tile per channel
    double T[4][64];      // row-transform staging
    double C[64];         // fp32-cast orthonormal DCT matrix (as double)
};

// Per-tile rounded YCbCr + 2D DCT (double accumulation, fp32 matrix entries to
// match the reference's fp32 DCT_M values). tile == wave (64 lanes).
__device__ __forceinline__ void dct_tile(const float* __restrict__ rgb, int gt,
                                         int tile, int lane, TileSmem& sm,
                                         double d3[3]) {
    if (threadIdx.x < 64) {
        int k = threadIdx.x >> 3, nn = threadIdx.x & 7;
        double v = 0.5 * cos((2.0 * nn + 1.0) * (double)k * M_PI / 16.0);
        if (k == 0) v *= 0.70710678118654752440;
        sm.C[threadIdx.x] = (double)(float)v;   // reference casts DCT_M to fp32
    }
    int b = gt >> 12, n = gt & 4095;
    int i = n >> 6, j = n & 63;
    int r = lane >> 3, s = lane & 7;
    int pix = ((b * HH + i * 8 + r) * WW + (j * 8 + s)) * 3;
    double R = rgb[pix], G = rgb[pix + 1], Bv = rgb[pix + 2];
    // hard_round(rgb @ RGB2YCC^T + off) - 128, fp32 matrix constants, double dot
    double Y  = rint(R * (double)0.299f     + G * (double)0.587f     + Bv * (double)0.114f     + 0.0)   - 128.0;
    double Cb = rint(R * (double)-0.168736f + G * (double)-0.331264f + Bv * (double)0.5f       + 128.0) - 128.0;
    double Cr = rint(R * (double)0.5f       + G * (double)-0.418688f + Bv * (double)-0.081312f + 128.0) - 128.0;
    sm.X[tile][0][lane] = Y;
    sm.X[tile][1][lane] = Cb;
    sm.X[tile][2][lane] = Cr;
    __syncthreads();
    for (int ch = 0; ch < 3; ++ch) {
        // T[r][v] = sum_s X[r][s]*C[v][s]   (lane maps to (r, v=s))
        double t = 0.0;
        #pragma unroll
        for (int ss = 0; ss < 8; ++ss)
            t += sm.X[tile][ch][r * 8 + ss] * sm.C[s * 8 + ss];
        __syncthreads();                 // previous iteration's T readers done
        sm.T[tile][lane] = t;
        __syncthreads();
        // d[u][v] = sum_r C[u][r]*T[r][v]   (lane maps to (u=r, v=s))
        double d = 0.0;
        #pragma unroll
        for (int rr = 0; rr < 8; ++rr)
            d += sm.C[r * 8 + rr] * sm.T[tile][rr * 8 + s];
        d3[ch] = d;
    }
}

__global__ __launch_bounds__(256) void k_energy(const float* __restrict__ rgb,
                                                double* __restrict__ ey,
                                                double* __restrict__ ec,
                                                double* __restrict__ dstore,
                                                int use_store) {
    __shared__ TileSmem sm;
    int tid = threadIdx.x, tile = tid >> 6, lane = tid & 63;
    int gt = blockIdx.x * 4 + tile;
    double d3[3];
    dct_tile(rgb, gt, tile, lane, sm, d3);
    if (use_store) {
        #pragma unroll
        for (int ch = 0; ch < 3; ++ch)
            dstore[((size_t)ch * NTILES + gt) * 64 + lane] = d3[ch];
    }
    double e[3];
    #pragma unroll
    for (int ch = 0; ch < 3; ++ch) {
        double v = d3[ch] * d3[ch];
        #pragma unroll
        for (int off = 1; off < 64; off <<= 1) v += __shfl_xor(v, off);
        double dc = __shfl(d3[ch], 0);
        e[ch] = log1p(v - dc * dc + 1e-6);
    }
    if (lane == 0) {
        ey[gt] = e[0];
        ec[gt] = 0.5 * (e[1] + e[2]);
    }
}

__global__ __launch_bounds__(256) void k_minmax(const double* __restrict__ ey,
                                                const double* __restrict__ ec,
                                                double* __restrict__ mm,
                                                float* __restrict__ out_tail) {
    __shared__ double s0[256], s1[256], s2[256], s3[256];
    int b = blockIdx.x, tid = threadIdx.x;
    double mny = 1e300, mxy = -1e300, mnc = 1e300, mxc = -1e300;
    for (int n = tid; n < NB; n += 256) {
        double vy = ey[b * NB + n], vc = ec[b * NB + n];
        mny = fmin(mny, vy); mxy = fmax(mxy, vy);
        mnc = fmin(mnc, vc); mxc = fmax(mxc, vc);
    }
    s0[tid] = mny; s1[tid] = mxy; s2[tid] = mnc; s3[tid] = mxc;
    __syncthreads();
    for (int off = 128; off > 0; off >>= 1) {
        if (tid < off) {
            s0[tid] = fmin(s0[tid], s0[tid + off]);
            s1[tid] = fmax(s1[tid], s1[tid + off]);
            s2[tid] = fmin(s2[tid], s2[tid + off]);
            s3[tid] = fmax(s3[tid], s3[tid + off]);
        }
        __syncthreads();
    }
    if (tid == 0) {
        mm[b] = s0[0]; mm[32 + b] = s1[0]; mm[64 + b] = s2[0]; mm[96 + b] = s3[0];
        double ry = (s1[0] - s0[0]) / (s1[0] - s0[0] + 1e-6);
        double rc = (s3[0] - s2[0]) / (s3[0] - s2[0] + 1e-6);
        // min/max of enc_qf over pixels = monotone map of rank extremes (0, rmax)
        out_tail[b]      = (float)qf_from_rank(0.0);   // y_qf_min
        out_tail[32 + b] = (float)qf_from_rank(ry);    // y_qf_max
        out_tail[64 + b] = (float)qf_from_rank(0.0);   // c_qf_min
        out_tail[96 + b] = (float)qf_from_rank(rc);    // c_qf_max
    }
}

__global__ __launch_bounds__(256) void k_quant(const float* __restrict__ rgb,
                                               const double* __restrict__ ey,
                                               const double* __restrict__ ec,
                                               const double* __restrict__ mm,
                                               const double* __restrict__ dstore,
                                               int use_store,
                                               float* __restrict__ out) {
    __shared__ TileSmem sm;
    int tid = threadIdx.x, tile = tid >> 6, lane = tid & 63;
    int gt = blockIdx.x * 4 + tile;
    double d3[3];
    if (use_store) {
        #pragma unroll
        for (int ch = 0; ch < 3; ++ch)
            d3[ch] = dstore[((size_t)ch * NTILES + gt) * 64 + lane];
    } else {
        dct_tile(rgb, gt, tile, lane, sm, d3);
    }
    int b = gt >> 12, n = gt & 4095;
    int i = n >> 6, j = n & 63;
    int r = lane >> 3, s = lane & 7;

    double eyv = ey[gt], ecv = ec[gt];
    double mny = mm[b], mxy = mm[32 + b], mnc = mm[64 + b], mxc = mm[96 + b];
    double ry = (eyv - mny) / (mxy - mny + 1e-6);
    double rc = (ecv - mnc) / (mxc - mnc + 1e-6);
    double qy = qf_from_rank(ry), qc = qf_from_rank(rc);
    double sy = scale_from_qf(qy), sc = scale_from_qf(qc);

    // pixel maps: enc_qf / enc_scale, interleaved [y, c] per pixel -> float2
    int px = (b * HH + i * 8 + r) * WW + (j * 8 + s);
    ((float2*)(out + 2 * (size_t)QD))[px]      = make_float2((float)qy, (float)qc);
    ((float2*)(out + 2 * (size_t)QD + PP))[px] = make_float2((float)sy, (float)sc);

    // quantized DCT
    size_t qbase = ((size_t)(b * 3) * NB + n) * 64 + lane;
    out[qbase]                        = (float)rint(d3[0] / (sy * (double)c_yq[lane]));
    out[qbase + (size_t)NB * 64]      = (float)rint(d3[1] / (sc * (double)c_cq[lane]));
    out[qbase + 2 * (size_t)NB * 64]  = (float)rint(d3[2] / (sc * (double)c_cq[lane]));
}

__global__ __launch_bounds__(256) void k_blocks(const float* __restrict__ out_q,
                                                float* __restrict__ out_b) {
    int tid = threadIdx.x;
    int gt = blockIdx.x * 4 + (tid >> 6);   // over BB*3*NB = 393216 (b,ch,n) rows
    int lane = tid & 63;
    int n = gt & 4095;
    int zz = c_zz[lane];
    size_t base = (size_t)gt * 64;
    float cur = out_q[base + zz];
    float delta = cur;
    if (n > 0) delta = cur - out_q[base - 64 + zz];
    out_b[base + lane] =
        (float)(log(fabs((double)delta) + 1.0) / 0.69314718055994530942);
}

extern "C" void kernel_launch(void* const* d_in, const int* in_sizes, int n_in,
                              void* d_out, int out_size, void* d_ws, size_t ws_size,
                              hipStream_t stream) {
    const float* rgb = (const float*)d_in[0];
    float* out = (float*)d_out;
    double* ws = (double*)d_ws;
    double* ey = ws;
    double* ec = ws + NTILES;
    double* mm = ws + 2 * (size_t)NTILES;            // [mny|mxy|mnc|mxc] x 32
    double* dstore = ws + 2 * (size_t)NTILES + 128;  // optional DCT coeff cache
    size_t need = (2 * (size_t)NTILES + 128 + 3 * (size_t)NTILES * 64) * sizeof(double);
    int use_store = (ws_size >= need) ? 1 : 0;

    dim3 blk(256);
    k_energy<<<NTILES / 4, blk, 0, stream>>>(rgb, ey, ec, dstore, use_store);
    k_minmax<<<BB, blk, 0, stream>>>(ey, ec, mm, out + TAILOFF);
    k_quant<<<NTILES / 4, blk, 0, stream>>>(rgb, ey, ec, mm, dstore, use_store, out);
    k_blocks<<<(BB * 3 * NB) / 4, blk, 0, stream>>>(out, out + QD);
}